// Round 1
// baseline (1740.088 us; speedup 1.0000x reference)
//
#include <hip/hip_runtime.h>

#define NN 50000
#define NE 800000
#define HIDN 256
#define AF 256
#define BF 128
#define KT 384

typedef __attribute__((ext_vector_type(8))) short short8;
typedef __attribute__((ext_vector_type(4))) float f32x4;

__device__ __forceinline__ unsigned short f2bf(float f) {
    union { float f; unsigned int u; } c; c.f = f;
    unsigned int u = c.u;
    return (unsigned short)((u + 0x7FFFu + ((u >> 16) & 1u)) >> 16);
}

// ---------------------------------------------------------------- scatter
__global__ __launch_bounds__(256) void k_scatter(const float* __restrict__ w,
        const int* __restrict__ dst, float* __restrict__ aggw, int* __restrict__ deg) {
    int gid = blockIdx.x * 256 + threadIdx.x;   // NE*32 threads
    int e = gid >> 5;
    int q = gid & 31;
    if (e >= NE) return;
    int d = dst[e];
    const float4 v = reinterpret_cast<const float4*>(w + (size_t)e * BF)[q];
    float* p = aggw + (size_t)d * BF + q * 4;
    atomicAdd(p + 0, v.x);
    atomicAdd(p + 1, v.y);
    atomicAdd(p + 2, v.z);
    atomicAdd(p + 3, v.w);
    if (q == 0) atomicAdd(deg + d, 1);
}

// ------------------------------------------------- pack [W_atom|W_bond] -> bf16
__global__ __launch_bounds__(256) void k_convert(const float* __restrict__ Wa,
        const float* __restrict__ Wb, unsigned short* __restrict__ Wc) {
    int gid = blockIdx.x * 256 + threadIdx.x;   // 12288 threads, 8 elems each
    int j = gid / 48, cb = gid % 48;
    const float* src = (cb < 32) ? (Wa + j * AF + cb * 8) : (Wb + j * BF + (cb - 32) * 8);
    float4 a = reinterpret_cast<const float4*>(src)[0];
    float4 b = reinterpret_cast<const float4*>(src)[1];
    short8 s;
    s[0] = f2bf(a.x); s[1] = f2bf(a.y); s[2] = f2bf(a.z); s[3] = f2bf(a.w);
    s[4] = f2bf(b.x); s[5] = f2bf(b.y); s[6] = f2bf(b.z); s[7] = f2bf(b.w);
    *reinterpret_cast<short8*>(Wc + j * KT + cb * 8) = s;
}

// ------------------------------- fused node GEMM + bias + deg*b_bond + relu + stats
__global__ __launch_bounds__(256) void k_gemm(const float* __restrict__ x,
        const float* __restrict__ aggw, const int* __restrict__ deg,
        const unsigned short* __restrict__ Wc, const float* __restrict__ b_atom,
        const float* __restrict__ b_bond, float* __restrict__ out,
        float* __restrict__ colsum, float* __restrict__ colsumsq) {
    __shared__ unsigned short feat[64][392];   // stride 392 (784B): row stride %32 banks = 4
    const int tid = threadIdx.x;
    const int row0 = blockIdx.x * 64;

    // stage [x | aggw] rows -> bf16 LDS. 64 rows x 48 col-blocks of 8
    #pragma unroll
    for (int i = 0; i < 12; ++i) {
        int idx = i * 256 + tid;
        int r = idx / 48, cb = idx % 48;
        int grow = row0 + r;
        float4 a = make_float4(0.f, 0.f, 0.f, 0.f), b = make_float4(0.f, 0.f, 0.f, 0.f);
        if (grow < NN) {
            const float* src = (cb < 32) ? (x + (size_t)grow * AF + cb * 8)
                                         : (aggw + (size_t)grow * BF + (cb - 32) * 8);
            a = reinterpret_cast<const float4*>(src)[0];
            b = reinterpret_cast<const float4*>(src)[1];
        }
        short8 s;
        s[0] = f2bf(a.x); s[1] = f2bf(a.y); s[2] = f2bf(a.z); s[3] = f2bf(a.w);
        s[4] = f2bf(b.x); s[5] = f2bf(b.y); s[6] = f2bf(b.z); s[7] = f2bf(b.w);
        *reinterpret_cast<short8*>(&feat[r][cb * 8]) = s;
    }
    __syncthreads();

    const int wave = tid >> 6, lane = tid & 63;
    const int lrow = lane & 15, lkb = (lane >> 4) * 8;
    f32x4 acc[16];
    #pragma unroll
    for (int t = 0; t < 16; ++t) acc[t] = f32x4{0.f, 0.f, 0.f, 0.f};

    const unsigned short* frow = &feat[wave * 16 + lrow][0];
    #pragma unroll
    for (int kt = 0; kt < 12; ++kt) {
        const int kg = kt * 32 + lkb;
        short8 afrag = *reinterpret_cast<const short8*>(frow + kg);
        #pragma unroll
        for (int t = 0; t < 16; ++t) {
            short8 bfrag = *reinterpret_cast<const short8*>(Wc + (t * 16 + lrow) * KT + kg);
            acc[t] = __builtin_amdgcn_mfma_f32_16x16x32_bf16(afrag, bfrag, acc[t], 0, 0, 0);
        }
    }

    // epilogue: bias + deg*b_bond + relu + store + column stats
    const int m0 = (lane >> 4) * 4;
    const int growb = row0 + wave * 16 + m0;
    float degv[4];
    #pragma unroll
    for (int r2 = 0; r2 < 4; ++r2)
        degv[r2] = (growb + r2 < NN) ? (float)deg[growb + r2] : 0.f;

    #pragma unroll
    for (int t = 0; t < 16; ++t) {
        const int col = t * 16 + lrow;
        const float ba = b_atom[col], bb = b_bond[col];
        float s = 0.f, s2 = 0.f;
        #pragma unroll
        for (int r2 = 0; r2 < 4; ++r2) {
            const int gr = growb + r2;
            float v = acc[t][r2] + ba + degv[r2] * bb;
            v = fmaxf(v, 0.f);
            if (gr < NN) {
                out[(size_t)gr * HIDN + col] = v;
                s += v;
                s2 += v * v;
            }
        }
        s  += __shfl_xor(s, 16);  s  += __shfl_xor(s, 32);
        s2 += __shfl_xor(s2, 16); s2 += __shfl_xor(s2, 32);
        if (lane < 16) {
            atomicAdd(colsum + col, s);
            atomicAdd(colsumsq + col, s2);
        }
    }
}

// ---------------------------------------------------------------- BN finalize
__global__ void k_bnfin(const float* __restrict__ colsum, const float* __restrict__ colsumsq,
        const float* __restrict__ gamma, const float* __restrict__ beta,
        float* __restrict__ scale, float* __restrict__ shift) {
    int j = threadIdx.x;
    float mean = colsum[j] * (1.f / NN);
    float var = colsumsq[j] * (1.f / NN) - mean * mean;
    float sc = gamma[j] * rsqrtf(var + 1e-5f);
    scale[j] = sc;
    shift[j] = beta[j] - mean * sc;
}

// ---------------------------------------------------------------- BN apply (in-place)
__global__ __launch_bounds__(256) void k_bnapply(float* __restrict__ out,
        const float* __restrict__ scale, const float* __restrict__ shift) {
    int gid = blockIdx.x * 256 + threadIdx.x;
    if (gid >= NN * HIDN / 4) return;
    float4 v = reinterpret_cast<float4*>(out)[gid];
    int cb = (gid * 4) & (HIDN - 1);
    const float4 sc = *reinterpret_cast<const float4*>(scale + cb);
    const float4 sh = *reinterpret_cast<const float4*>(shift + cb);
    v.x = fmaf(v.x, sc.x, sh.x);
    v.y = fmaf(v.y, sc.y, sh.y);
    v.z = fmaf(v.z, sc.z, sh.z);
    v.w = fmaf(v.w, sc.w, sh.w);
    reinterpret_cast<float4*>(out)[gid] = v;
}

extern "C" void kernel_launch(void* const* d_in, const int* in_sizes, int n_in,
                              void* d_out, int out_size, void* d_ws, size_t ws_size,
                              hipStream_t stream) {
    const float* x      = (const float*)d_in[0];
    const float* w      = (const float*)d_in[1];
    const int*   dst    = (const int*)d_in[2];
    const float* W_atom = (const float*)d_in[3];
    const float* b_atom = (const float*)d_in[4];
    const float* W_bond = (const float*)d_in[5];
    const float* b_bond = (const float*)d_in[6];
    const float* gamma  = (const float*)d_in[7];
    const float* beta   = (const float*)d_in[8];
    float* out = (float*)d_out;

    // workspace layout
    float* aggw = (float*)d_ws;                                  // 50000*128 f32 = 25.6 MB
    int* deg = (int*)(aggw + (size_t)NN * BF);                   // 50000 int
    unsigned short* Wc = (unsigned short*)(deg + NN);            // 256*384 bf16
    float* colsum   = (float*)(Wc + (size_t)HIDN * KT);          // 256
    float* colsumsq = colsum + HIDN;                             // 256
    float* scale    = colsumsq + HIDN;                           // 256
    float* shift    = scale + HIDN;                              // 256

    const size_t zero_bytes = (size_t)NN * BF * 4 + (size_t)NN * 4
                            + (size_t)HIDN * KT * 2 + 4 * HIDN * 4;
    hipMemsetAsync(d_ws, 0, zero_bytes, stream);

    k_convert<<<48, 256, 0, stream>>>(W_atom, W_bond, Wc);
    k_scatter<<<(NE * 32) / 256, 256, 0, stream>>>(w, dst, aggw, deg);
    k_gemm<<<(NN + 63) / 64, 256, 0, stream>>>(x, aggw, deg, Wc, b_atom, b_bond,
                                               out, colsum, colsumsq);
    k_bnfin<<<1, 256, 0, stream>>>(colsum, colsumsq, gamma, beta, scale, shift);
    k_bnapply<<<(NN * HIDN / 4 + 255) / 256, 256, 0, stream>>>(out, scale, shift);
}

// Round 2
// 594.761 us; speedup vs baseline: 2.9257x; 2.9257x over previous
//
#include <hip/hip_runtime.h>

#define NN 50000
#define NE 800000
#define HIDN 256
#define AF 256
#define BF 128
#define KT 384

typedef __attribute__((ext_vector_type(8))) short short8;
typedef __attribute__((ext_vector_type(4))) float f32x4;

__device__ __forceinline__ unsigned short f2bf(float f) {
    union { float f; unsigned int u; } c; c.f = f;
    unsigned int u = c.u;
    return (unsigned short)((u + 0x7FFFu + ((u >> 16) & 1u)) >> 16);
}

// ---------------------------------------------------------------- histogram of dst
__global__ __launch_bounds__(256) void k_hist(const int* __restrict__ dst,
        int* __restrict__ count) {
    int e = blockIdx.x * 256 + threadIdx.x;
    if (e < NE) atomicAdd(count + dst[e], 1);
}

// ------------------------------------------- exclusive scan (single block, 1024 thr)
__global__ __launch_bounds__(1024) void k_scan(const int* __restrict__ count,
        int* __restrict__ offset, int* __restrict__ cursor) {
    __shared__ int partial[1024];
    const int per = (NN + 1023) / 1024;   // 49
    const int t = threadIdx.x;
    const int base = t * per;
    int s = 0;
    for (int i = 0; i < per; ++i) {
        int idx = base + i;
        if (idx < NN) s += count[idx];
    }
    partial[t] = s;
    __syncthreads();
    for (int off = 1; off < 1024; off <<= 1) {
        int v = (t >= off) ? partial[t - off] : 0;
        __syncthreads();
        partial[t] += v;
        __syncthreads();
    }
    int run = (t == 0) ? 0 : partial[t - 1];
    for (int i = 0; i < per; ++i) {
        int idx = base + i;
        if (idx < NN) {
            offset[idx] = run;
            cursor[idx] = run;
            run += count[idx];
        }
    }
}

// ---------------------------------------------------------------- bin edge ids by dst
__global__ __launch_bounds__(256) void k_sortscatter(const int* __restrict__ dst,
        int* __restrict__ cursor, int* __restrict__ sortedEdge) {
    int e = blockIdx.x * 256 + threadIdx.x;
    if (e >= NE) return;
    int d = dst[e];
    int pos = atomicAdd(cursor + d, 1);
    sortedEdge[pos] = e;
}

// ------------------------------------------------- gather: wave per node, no atomics
__global__ __launch_bounds__(256) void k_gather(const float* __restrict__ w,
        const int* __restrict__ sortedEdge, const int* __restrict__ offset,
        const int* __restrict__ count, float* __restrict__ aggw) {
    const int node = blockIdx.x * 4 + (threadIdx.x >> 6);
    const int lane = threadIdx.x & 63;
    if (node >= NN) return;
    const int start = offset[node];
    const int degn = count[node];
    const float2* __restrict__ w2 = reinterpret_cast<const float2*>(w);
    float ax = 0.f, ay = 0.f;
    for (int base = 0; base < degn; base += 64) {
        const int m = min(64, degn - base);
        int eid = 0;
        if (lane < m) eid = sortedEdge[start + base + lane];
        int i = 0;
        for (; i + 4 <= m; i += 4) {
            int e0 = __shfl(eid, i);
            int e1 = __shfl(eid, i + 1);
            int e2 = __shfl(eid, i + 2);
            int e3 = __shfl(eid, i + 3);
            float2 v0 = w2[(size_t)e0 * 64 + lane];
            float2 v1 = w2[(size_t)e1 * 64 + lane];
            float2 v2 = w2[(size_t)e2 * 64 + lane];
            float2 v3 = w2[(size_t)e3 * 64 + lane];
            ax += (v0.x + v1.x) + (v2.x + v3.x);
            ay += (v0.y + v1.y) + (v2.y + v3.y);
        }
        for (; i < m; ++i) {
            int e = __shfl(eid, i);
            float2 v = w2[(size_t)e * 64 + lane];
            ax += v.x;
            ay += v.y;
        }
    }
    reinterpret_cast<float2*>(aggw)[(size_t)node * 64 + lane] = make_float2(ax, ay);
}

// ------------------------------------------------- pack [W_atom|W_bond] -> bf16
__global__ __launch_bounds__(256) void k_convert(const float* __restrict__ Wa,
        const float* __restrict__ Wb, unsigned short* __restrict__ Wc) {
    int gid = blockIdx.x * 256 + threadIdx.x;   // 12288 threads, 8 elems each
    int j = gid / 48, cb = gid % 48;
    const float* src = (cb < 32) ? (Wa + j * AF + cb * 8) : (Wb + j * BF + (cb - 32) * 8);
    float4 a = reinterpret_cast<const float4*>(src)[0];
    float4 b = reinterpret_cast<const float4*>(src)[1];
    short8 s;
    s[0] = f2bf(a.x); s[1] = f2bf(a.y); s[2] = f2bf(a.z); s[3] = f2bf(a.w);
    s[4] = f2bf(b.x); s[5] = f2bf(b.y); s[6] = f2bf(b.z); s[7] = f2bf(b.w);
    *reinterpret_cast<short8*>(Wc + j * KT + cb * 8) = s;
}

// ------------------------------- fused node GEMM + bias + deg*b_bond + relu + stats
__global__ __launch_bounds__(256) void k_gemm(const float* __restrict__ x,
        const float* __restrict__ aggw, const int* __restrict__ deg,
        const unsigned short* __restrict__ Wc, const float* __restrict__ b_atom,
        const float* __restrict__ b_bond, float* __restrict__ out,
        float* __restrict__ colsum, float* __restrict__ colsumsq) {
    __shared__ unsigned short feat[64][392];   // stride 392 (784B): row stride %32 banks = 4
    const int tid = threadIdx.x;
    const int row0 = blockIdx.x * 64;

    // stage [x | aggw] rows -> bf16 LDS. 64 rows x 48 col-blocks of 8
    #pragma unroll
    for (int i = 0; i < 12; ++i) {
        int idx = i * 256 + tid;
        int r = idx / 48, cb = idx % 48;
        int grow = row0 + r;
        float4 a = make_float4(0.f, 0.f, 0.f, 0.f), b = make_float4(0.f, 0.f, 0.f, 0.f);
        if (grow < NN) {
            const float* src = (cb < 32) ? (x + (size_t)grow * AF + cb * 8)
                                         : (aggw + (size_t)grow * BF + (cb - 32) * 8);
            a = reinterpret_cast<const float4*>(src)[0];
            b = reinterpret_cast<const float4*>(src)[1];
        }
        short8 s;
        s[0] = f2bf(a.x); s[1] = f2bf(a.y); s[2] = f2bf(a.z); s[3] = f2bf(a.w);
        s[4] = f2bf(b.x); s[5] = f2bf(b.y); s[6] = f2bf(b.z); s[7] = f2bf(b.w);
        *reinterpret_cast<short8*>(&feat[r][cb * 8]) = s;
    }
    __syncthreads();

    const int wave = tid >> 6, lane = tid & 63;
    const int lrow = lane & 15, lkb = (lane >> 4) * 8;
    f32x4 acc[16];
    #pragma unroll
    for (int t = 0; t < 16; ++t) acc[t] = f32x4{0.f, 0.f, 0.f, 0.f};

    const unsigned short* frow = &feat[wave * 16 + lrow][0];
    #pragma unroll
    for (int kt = 0; kt < 12; ++kt) {
        const int kg = kt * 32 + lkb;
        short8 afrag = *reinterpret_cast<const short8*>(frow + kg);
        #pragma unroll
        for (int t = 0; t < 16; ++t) {
            short8 bfrag = *reinterpret_cast<const short8*>(Wc + (t * 16 + lrow) * KT + kg);
            acc[t] = __builtin_amdgcn_mfma_f32_16x16x32_bf16(afrag, bfrag, acc[t], 0, 0, 0);
        }
    }

    // epilogue: bias + deg*b_bond + relu + store + column stats
    const int m0 = (lane >> 4) * 4;
    const int growb = row0 + wave * 16 + m0;
    float degv[4];
    #pragma unroll
    for (int r2 = 0; r2 < 4; ++r2)
        degv[r2] = (growb + r2 < NN) ? (float)deg[growb + r2] : 0.f;

    #pragma unroll
    for (int t = 0; t < 16; ++t) {
        const int col = t * 16 + lrow;
        const float ba = b_atom[col], bb = b_bond[col];
        float s = 0.f, s2 = 0.f;
        #pragma unroll
        for (int r2 = 0; r2 < 4; ++r2) {
            const int gr = growb + r2;
            float v = acc[t][r2] + ba + degv[r2] * bb;
            v = fmaxf(v, 0.f);
            if (gr < NN) {
                out[(size_t)gr * HIDN + col] = v;
                s += v;
                s2 += v * v;
            }
        }
        s  += __shfl_xor(s, 16);  s  += __shfl_xor(s, 32);
        s2 += __shfl_xor(s2, 16); s2 += __shfl_xor(s2, 32);
        if (lane < 16) {
            atomicAdd(colsum + col, s);
            atomicAdd(colsumsq + col, s2);
        }
    }
}

// ---------------------------------------------------------------- BN finalize
__global__ void k_bnfin(const float* __restrict__ colsum, const float* __restrict__ colsumsq,
        const float* __restrict__ gamma, const float* __restrict__ beta,
        float* __restrict__ scale, float* __restrict__ shift) {
    int j = threadIdx.x;
    float mean = colsum[j] * (1.f / NN);
    float var = colsumsq[j] * (1.f / NN) - mean * mean;
    float sc = gamma[j] * rsqrtf(var + 1e-5f);
    scale[j] = sc;
    shift[j] = beta[j] - mean * sc;
}

// ---------------------------------------------------------------- BN apply (in-place)
__global__ __launch_bounds__(256) void k_bnapply(float* __restrict__ out,
        const float* __restrict__ scale, const float* __restrict__ shift) {
    int gid = blockIdx.x * 256 + threadIdx.x;
    if (gid >= NN * HIDN / 4) return;
    float4 v = reinterpret_cast<float4*>(out)[gid];
    int cb = (gid * 4) & (HIDN - 1);
    const float4 sc = *reinterpret_cast<const float4*>(scale + cb);
    const float4 sh = *reinterpret_cast<const float4*>(shift + cb);
    v.x = fmaf(v.x, sc.x, sh.x);
    v.y = fmaf(v.y, sc.y, sh.y);
    v.z = fmaf(v.z, sc.z, sh.z);
    v.w = fmaf(v.w, sc.w, sh.w);
    reinterpret_cast<float4*>(out)[gid] = v;
}

extern "C" void kernel_launch(void* const* d_in, const int* in_sizes, int n_in,
                              void* d_out, int out_size, void* d_ws, size_t ws_size,
                              hipStream_t stream) {
    const float* x      = (const float*)d_in[0];
    const float* w      = (const float*)d_in[1];
    const int*   dst    = (const int*)d_in[2];
    const float* W_atom = (const float*)d_in[3];
    const float* b_atom = (const float*)d_in[4];
    const float* W_bond = (const float*)d_in[5];
    const float* b_bond = (const float*)d_in[6];
    const float* gamma  = (const float*)d_in[7];
    const float* beta   = (const float*)d_in[8];
    float* out = (float*)d_out;

    // workspace layout (zeroed region first)
    int* count      = (int*)d_ws;                       // NN
    float* colsum   = (float*)(count + NN);             // 256
    float* colsumsq = colsum + HIDN;                    // 256
    float* scale    = colsumsq + HIDN;                  // 256
    float* shift    = scale + HIDN;                     // 256
    int* offset     = (int*)(shift + HIDN);             // NN
    int* cursor     = offset + NN;                      // NN
    int* sortedEdge = cursor + NN;                      // NE
    float* aggw     = (float*)(sortedEdge + NE);        // NN*BF
    unsigned short* Wc = (unsigned short*)(aggw + (size_t)NN * BF);  // HIDN*KT bf16

    const size_t zero_bytes = (size_t)NN * 4 + 4 * HIDN * 4;   // count + stats
    hipMemsetAsync(d_ws, 0, zero_bytes, stream);

    k_hist<<<(NE + 255) / 256, 256, 0, stream>>>(dst, count);
    k_scan<<<1, 1024, 0, stream>>>(count, offset, cursor);
    k_sortscatter<<<(NE + 255) / 256, 256, 0, stream>>>(dst, cursor, sortedEdge);
    k_gather<<<(NN + 3) / 4, 256, 0, stream>>>(w, sortedEdge, offset, count, aggw);
    k_convert<<<48, 256, 0, stream>>>(W_atom, W_bond, Wc);
    k_gemm<<<(NN + 63) / 64, 256, 0, stream>>>(x, aggw, count, Wc, b_atom, b_bond,
                                               out, colsum, colsumsq);
    k_bnfin<<<1, 256, 0, stream>>>(colsum, colsumsq, gamma, beta, scale, shift);
    k_bnapply<<<(NN * HIDN / 4 + 255) / 256, 256, 0, stream>>>(out, scale, shift);
}

// Round 3
// 368.370 us; speedup vs baseline: 4.7237x; 1.6146x over previous
//
#include <hip/hip_runtime.h>

#define NN 50000
#define NE 800000
#define HIDN 256
#define AF 256
#define BF 128
#define KT 384
#define NCHUNK 1563   // ceil(NN/32)

typedef __attribute__((ext_vector_type(8))) short short8;
typedef __attribute__((ext_vector_type(4))) float f32x4;

__device__ __forceinline__ unsigned short f2bf(float f) {
    union { float f; unsigned int u; } c; c.f = f;
    unsigned int u = c.u;
    return (unsigned short)((u + 0x7FFFu + ((u >> 16) & 1u)) >> 16);
}

// ---------------------------------------------------------------- histogram of dst
__global__ __launch_bounds__(256) void k_hist(const int* __restrict__ dst,
        int* __restrict__ count) {
    int e = blockIdx.x * 256 + threadIdx.x;
    if (e < NE) atomicAdd(count + dst[e], 1);
}

// ------------------------------------------- exclusive scan (single block, 1024 thr)
__global__ __launch_bounds__(1024) void k_scan(const int* __restrict__ count,
        int* __restrict__ offset, int* __restrict__ cursor) {
    __shared__ int partial[1024];
    const int per = (NN + 1023) / 1024;   // 49
    const int t = threadIdx.x;
    const int base = t * per;
    int s = 0;
    for (int i = 0; i < per; ++i) {
        int idx = base + i;
        if (idx < NN) s += count[idx];
    }
    partial[t] = s;
    __syncthreads();
    for (int off = 1; off < 1024; off <<= 1) {
        int v = (t >= off) ? partial[t - off] : 0;
        __syncthreads();
        partial[t] += v;
        __syncthreads();
    }
    int run = (t == 0) ? 0 : partial[t - 1];
    for (int i = 0; i < per; ++i) {
        int idx = base + i;
        if (idx < NN) {
            offset[idx] = run;
            cursor[idx] = run;
            run += count[idx];
        }
    }
}

// ---------------------------------------------------------------- bin edge ids by dst
__global__ __launch_bounds__(256) void k_sortscatter(const int* __restrict__ dst,
        int* __restrict__ cursor, int* __restrict__ sortedEdge) {
    int e = blockIdx.x * 256 + threadIdx.x;
    if (e >= NE) return;
    int d = dst[e];
    int pos = atomicAdd(cursor + d, 1);
    sortedEdge[pos] = e;
}

// ----------------------------- gather: wave per node, no atomics, bf16 output rows
__global__ __launch_bounds__(256) void k_gather(const float* __restrict__ w,
        const int* __restrict__ sortedEdge, const int* __restrict__ offset,
        const int* __restrict__ count, unsigned short* __restrict__ agg) {
    const int node = blockIdx.x * 4 + (threadIdx.x >> 6);
    const int lane = threadIdx.x & 63;
    if (node >= NN) return;
    const int start = offset[node];
    const int degn = count[node];
    const float2* __restrict__ w2 = reinterpret_cast<const float2*>(w);
    float ax = 0.f, ay = 0.f;
    for (int base = 0; base < degn; base += 64) {
        const int m = min(64, degn - base);
        int eid = 0;
        if (lane < m) eid = sortedEdge[start + base + lane];
        int i = 0;
        for (; i + 4 <= m; i += 4) {
            int e0 = __shfl(eid, i);
            int e1 = __shfl(eid, i + 1);
            int e2 = __shfl(eid, i + 2);
            int e3 = __shfl(eid, i + 3);
            float2 v0 = w2[(size_t)e0 * 64 + lane];
            float2 v1 = w2[(size_t)e1 * 64 + lane];
            float2 v2 = w2[(size_t)e2 * 64 + lane];
            float2 v3 = w2[(size_t)e3 * 64 + lane];
            ax += (v0.x + v1.x) + (v2.x + v3.x);
            ay += (v0.y + v1.y) + (v2.y + v3.y);
        }
        for (; i < m; ++i) {
            int e = __shfl(eid, i);
            float2 v = w2[(size_t)e * 64 + lane];
            ax += v.x;
            ay += v.y;
        }
    }
    unsigned int pack = (unsigned int)f2bf(ax) | ((unsigned int)f2bf(ay) << 16);
    *reinterpret_cast<unsigned int*>(agg + (size_t)node * BF + lane * 2) = pack;
}

// ------------------------------------------------- pack [W_atom|W_bond] -> bf16 (linear)
__global__ __launch_bounds__(256) void k_convert(const float* __restrict__ Wa,
        const float* __restrict__ Wb, unsigned short* __restrict__ Wc) {
    int gid = blockIdx.x * 256 + threadIdx.x;   // 12288 threads, 8 elems each
    int j = gid / 48, cb = gid % 48;
    const float* src = (cb < 32) ? (Wa + j * AF + cb * 8) : (Wb + j * BF + (cb - 32) * 8);
    float4 a = reinterpret_cast<const float4*>(src)[0];
    float4 b = reinterpret_cast<const float4*>(src)[1];
    short8 s;
    s[0] = f2bf(a.x); s[1] = f2bf(a.y); s[2] = f2bf(a.z); s[3] = f2bf(a.w);
    s[4] = f2bf(b.x); s[5] = f2bf(b.y); s[6] = f2bf(b.z); s[7] = f2bf(b.w);
    *reinterpret_cast<short8*>(Wc + j * KT + cb * 8) = s;
}

// ------------------- fused node GEMM: B in registers, A LDS-staged (T14 async split)
__global__ __launch_bounds__(512, 1) void k_gemm(const float* __restrict__ x,
        const unsigned short* __restrict__ agg, const int* __restrict__ deg,
        const unsigned short* __restrict__ Wc, const float* __restrict__ b_atom,
        const float* __restrict__ b_bond, float* __restrict__ out,
        float* __restrict__ colsum, float* __restrict__ colsumsq) {
    __shared__ unsigned short As[32 * KT];   // 24576 B, XOR-swizzled in 16B chunks

    const int tid = threadIdx.x;
    const int cg  = blockIdx.x >> 7;         // col-group 0/1 (same rows -> same XCD)
    const int rb  = blockIdx.x & 127;
    const int wid = tid >> 6, lane = tid & 63;
    const int lrow = lane & 15, lk = lane >> 4;
    const int rh = wid & 1, cq = wid >> 1;   // row-half, col-quarter
    const int colb = cg * 128 + cq * 32;

    // ---- B fragments in registers (one-time, L2-resident)
    short8 breg[2][12];
    #pragma unroll
    for (int t = 0; t < 2; ++t)
        #pragma unroll
        for (int kt = 0; kt < 12; ++kt)
            breg[t][kt] = *reinterpret_cast<const short8*>(
                Wc + (size_t)(colb + t * 16 + lrow) * KT + kt * 32 + lk * 8);

    const float ba0 = b_atom[colb + lrow],      bb0 = b_bond[colb + lrow];
    const float ba1 = b_atom[colb + 16 + lrow], bb1 = b_bond[colb + 16 + lrow];

    // ---- staging registers
    float4 xa0, xb0, xa1, xb1;
    short8 ga;
    const int xr0 = tid >> 5, xkb = tid & 31;          // x task A: rows 0..15
    const int xr1 = 16 + (tid >> 5);                   // x task B: rows 16..31
    const int gr_ = tid >> 4, gkb = tid & 15;          // agg task

    auto loadchunk = [&](int ch) {
        const int base = ch * 32;
        int g0 = base + xr0, g1 = base + xr1, g2 = base + gr_;
        if (g0 < NN) {
            const float4* s = reinterpret_cast<const float4*>(x + (size_t)g0 * AF + xkb * 8);
            xa0 = s[0]; xb0 = s[1];
        } else { xa0 = make_float4(0,0,0,0); xb0 = make_float4(0,0,0,0); }
        if (g1 < NN) {
            const float4* s = reinterpret_cast<const float4*>(x + (size_t)g1 * AF + xkb * 8);
            xa1 = s[0]; xb1 = s[1];
        } else { xa1 = make_float4(0,0,0,0); xb1 = make_float4(0,0,0,0); }
        if (g2 < NN) {
            ga = *reinterpret_cast<const short8*>(agg + (size_t)g2 * BF + gkb * 8);
        } else { ga = short8{0,0,0,0,0,0,0,0}; }
    };
    auto writechunk = [&]() {
        short8 s;
        s[0]=f2bf(xa0.x); s[1]=f2bf(xa0.y); s[2]=f2bf(xa0.z); s[3]=f2bf(xa0.w);
        s[4]=f2bf(xb0.x); s[5]=f2bf(xb0.y); s[6]=f2bf(xb0.z); s[7]=f2bf(xb0.w);
        *reinterpret_cast<short8*>(As + xr0 * KT + ((xkb ^ (xr0 & 7)) << 3)) = s;
        s[0]=f2bf(xa1.x); s[1]=f2bf(xa1.y); s[2]=f2bf(xa1.z); s[3]=f2bf(xa1.w);
        s[4]=f2bf(xb1.x); s[5]=f2bf(xb1.y); s[6]=f2bf(xb1.z); s[7]=f2bf(xb1.w);
        *reinterpret_cast<short8*>(As + xr1 * KT + ((xkb ^ (xr1 & 7)) << 3)) = s;
        int kb = 32 + gkb;
        *reinterpret_cast<short8*>(As + gr_ * KT + ((kb ^ (gr_ & 7)) << 3)) = ga;
    };

    float st0 = 0.f, st20 = 0.f, st1 = 0.f, st21 = 0.f;
    const int ra = rh * 16 + lrow;

    loadchunk(rb);
    for (int chunk = rb; chunk < NCHUNK; chunk += 128) {
        writechunk();
        if (chunk + 128 < NCHUNK) loadchunk(chunk + 128);
        asm volatile("s_waitcnt lgkmcnt(0)" ::: "memory");
        __builtin_amdgcn_s_barrier();

        f32x4 acc0 = f32x4{0.f,0.f,0.f,0.f};
        f32x4 acc1 = f32x4{0.f,0.f,0.f,0.f};
        #pragma unroll
        for (int kt = 0; kt < 12; ++kt) {
            const int kb = kt * 4 + lk;
            short8 af = *reinterpret_cast<const short8*>(As + ra * KT + ((kb ^ (ra & 7)) << 3));
            acc0 = __builtin_amdgcn_mfma_f32_16x16x32_bf16(af, breg[0][kt], acc0, 0, 0, 0);
            acc1 = __builtin_amdgcn_mfma_f32_16x16x32_bf16(af, breg[1][kt], acc1, 0, 0, 0);
        }

        // epilogue: bias + deg*b_bond + relu + store + local stats
        const int row0 = chunk * 32 + rh * 16 + lk * 4;
        float degv[4];
        #pragma unroll
        for (int r2 = 0; r2 < 4; ++r2)
            degv[r2] = (row0 + r2 < NN) ? (float)deg[row0 + r2] : 0.f;
        #pragma unroll
        for (int r2 = 0; r2 < 4; ++r2) {
            const int gr = row0 + r2;
            float v0 = fmaxf(acc0[r2] + ba0 + degv[r2] * bb0, 0.f);
            float v1 = fmaxf(acc1[r2] + ba1 + degv[r2] * bb1, 0.f);
            if (gr < NN) {
                out[(size_t)gr * HIDN + colb + lrow]      = v0;
                out[(size_t)gr * HIDN + colb + 16 + lrow] = v1;
                st0 += v0; st20 += v0 * v0;
                st1 += v1; st21 += v1 * v1;
            }
        }
        asm volatile("s_waitcnt lgkmcnt(0)" ::: "memory");
        __builtin_amdgcn_s_barrier();
    }

    // flush stats: one atomic pair per (wave, t)
    float s, s2;
    s = st0; s2 = st20;
    s += __shfl_xor(s, 16);  s += __shfl_xor(s, 32);
    s2 += __shfl_xor(s2, 16); s2 += __shfl_xor(s2, 32);
    if (lane < 16) {
        atomicAdd(colsum + colb + lrow, s);
        atomicAdd(colsumsq + colb + lrow, s2);
    }
    s = st1; s2 = st21;
    s += __shfl_xor(s, 16);  s += __shfl_xor(s, 32);
    s2 += __shfl_xor(s2, 16); s2 += __shfl_xor(s2, 32);
    if (lane < 16) {
        atomicAdd(colsum + colb + 16 + lrow, s);
        atomicAdd(colsumsq + colb + 16 + lrow, s2);
    }
}

// ---------------------------------------------------------------- BN finalize
__global__ void k_bnfin(const float* __restrict__ colsum, const float* __restrict__ colsumsq,
        const float* __restrict__ gamma, const float* __restrict__ beta,
        float* __restrict__ scale, float* __restrict__ shift) {
    int j = threadIdx.x;
    float mean = colsum[j] * (1.f / NN);
    float var = colsumsq[j] * (1.f / NN) - mean * mean;
    float sc = gamma[j] * rsqrtf(var + 1e-5f);
    scale[j] = sc;
    shift[j] = beta[j] - mean * sc;
}

// ---------------------------------------------------------------- BN apply (in-place)
__global__ __launch_bounds__(256) void k_bnapply(float* __restrict__ out,
        const float* __restrict__ scale, const float* __restrict__ shift) {
    int gid = blockIdx.x * 256 + threadIdx.x;
    if (gid >= NN * HIDN / 4) return;
    float4 v = reinterpret_cast<float4*>(out)[gid];
    int cb = (gid * 4) & (HIDN - 1);
    const float4 sc = *reinterpret_cast<const float4*>(scale + cb);
    const float4 sh = *reinterpret_cast<const float4*>(shift + cb);
    v.x = fmaf(v.x, sc.x, sh.x);
    v.y = fmaf(v.y, sc.y, sh.y);
    v.z = fmaf(v.z, sc.z, sh.z);
    v.w = fmaf(v.w, sc.w, sh.w);
    reinterpret_cast<float4*>(out)[gid] = v;
}

extern "C" void kernel_launch(void* const* d_in, const int* in_sizes, int n_in,
                              void* d_out, int out_size, void* d_ws, size_t ws_size,
                              hipStream_t stream) {
    const float* x      = (const float*)d_in[0];
    const float* w      = (const float*)d_in[1];
    const int*   dst    = (const int*)d_in[2];
    const float* W_atom = (const float*)d_in[3];
    const float* b_atom = (const float*)d_in[4];
    const float* W_bond = (const float*)d_in[5];
    const float* b_bond = (const float*)d_in[6];
    const float* gamma  = (const float*)d_in[7];
    const float* beta   = (const float*)d_in[8];
    float* out = (float*)d_out;

    // workspace layout
    unsigned short* agg = (unsigned short*)d_ws;            // NN*128 bf16 = 12.8 MB
    unsigned short* Wc  = agg + (size_t)NN * BF;            // 256*384 bf16
    float* colsum   = (float*)(Wc + (size_t)HIDN * KT);     // 256
    float* colsumsq = colsum + HIDN;                        // 256
    int* count      = (int*)(colsumsq + HIDN);              // NN
    int* offset     = count + NN;                           // NN
    int* cursor     = offset + NN;                          // NN
    int* sortedEdge = cursor + NN;                          // NE
    float* scale    = (float*)(sortedEdge + NE);            // 256
    float* shift    = scale + HIDN;                         // 256

    // zero colsum+colsumsq+count (contiguous)
    hipMemsetAsync((void*)colsum, 0, (size_t)(2 * HIDN + NN) * 4, stream);

    k_convert<<<48, 256, 0, stream>>>(W_atom, W_bond, Wc);
    k_hist<<<(NE + 255) / 256, 256, 0, stream>>>(dst, count);
    k_scan<<<1, 1024, 0, stream>>>(count, offset, cursor);
    k_sortscatter<<<(NE + 255) / 256, 256, 0, stream>>>(dst, cursor, sortedEdge);
    k_gather<<<(NN + 3) / 4, 256, 0, stream>>>(w, sortedEdge, offset, count, agg);
    k_gemm<<<256, 512, 0, stream>>>(x, agg, count, Wc, b_atom, b_bond,
                                    out, colsum, colsumsq);
    k_bnfin<<<1, 256, 0, stream>>>(colsum, colsumsq, gamma, beta, scale, shift);
    k_bnapply<<<(NN * HIDN / 4 + 255) / 256, 256, 0, stream>>>(out, scale, shift);
}

// Round 4
// 236.388 us; speedup vs baseline: 7.3612x; 1.5583x over previous
//
#include <hip/hip_runtime.h>

#define NN 50000
#define NE 800000
#define HIDN 256
#define AF 256
#define BF 128
#define KT 384
#define NCHUNK 1563   // ceil(NN/32)

typedef __attribute__((ext_vector_type(8))) short short8;
typedef __attribute__((ext_vector_type(4))) float f32x4;
typedef __attribute__((ext_vector_type(2))) float f32x2;

__device__ __forceinline__ unsigned short f2bf(float f) {
    union { float f; unsigned int u; } c; c.f = f;
    unsigned int u = c.u;
    return (unsigned short)((u + 0x7FFFu + ((u >> 16) & 1u)) >> 16);
}

// ---------------------------------------------------------------- histogram of dst
__global__ __launch_bounds__(256) void k_hist(const int4* __restrict__ dst4,
        int* __restrict__ count) {
    int i = blockIdx.x * 256 + threadIdx.x;
    if (i < NE / 4) {
        int4 d = dst4[i];
        atomicAdd(count + d.x, 1);
        atomicAdd(count + d.y, 1);
        atomicAdd(count + d.z, 1);
        atomicAdd(count + d.w, 1);
    }
}

// ------------------------------------------- scan pass A: per-1024-block local scan
__global__ __launch_bounds__(1024) void k_scanA(const int* __restrict__ count,
        int* __restrict__ offset, int* __restrict__ blockSum) {
    __shared__ int sd[1024];
    const int t = threadIdx.x;
    const int idx = blockIdx.x * 1024 + t;
    int v = (idx < NN) ? count[idx] : 0;
    sd[t] = v;
    __syncthreads();
    for (int off = 1; off < 1024; off <<= 1) {
        int u = (t >= off) ? sd[t - off] : 0;
        __syncthreads();
        sd[t] += u;
        __syncthreads();
    }
    if (idx < NN) offset[idx] = sd[t] - v;   // local exclusive
    if (t == 1023) blockSum[blockIdx.x] = sd[1023];
}

// ------------------------------------------- scan pass B: scan 49 block totals
__global__ void k_scanB(const int* __restrict__ blockSum, int* __restrict__ blockBase) {
    const int t = threadIdx.x;   // 64
    int o = (t < 49) ? blockSum[t] : 0;
    int v = o;
    for (int off = 1; off < 64; off <<= 1) {
        int u = __shfl_up(v, off);
        if (t >= off) v += u;
    }
    if (t < 49) blockBase[t] = v - o;
}

// ------------------------------------------- scan pass C: add base, init cursor
__global__ __launch_bounds__(1024) void k_scanC(int* __restrict__ offset,
        int* __restrict__ cursor, const int* __restrict__ blockBase) {
    const int idx = blockIdx.x * 1024 + threadIdx.x;
    if (idx < NN) {
        int o = offset[idx] + blockBase[blockIdx.x];
        offset[idx] = o;
        cursor[idx] = o;
    }
}

// ---------------------------------------------------------------- bin edge ids by dst
__global__ __launch_bounds__(256) void k_sortscatter(const int4* __restrict__ dst4,
        int* __restrict__ cursor, int* __restrict__ sortedEdge) {
    int i = blockIdx.x * 256 + threadIdx.x;
    if (i >= NE / 4) return;
    int4 d = dst4[i];
    int e = i * 4;
    sortedEdge[atomicAdd(cursor + d.x, 1)] = e;
    sortedEdge[atomicAdd(cursor + d.y, 1)] = e + 1;
    sortedEdge[atomicAdd(cursor + d.z, 1)] = e + 2;
    sortedEdge[atomicAdd(cursor + d.w, 1)] = e + 3;
}

// ----------------------------- gather: wave per node, no atomics, bf16 output rows
__global__ __launch_bounds__(256) void k_gather(const float* __restrict__ w,
        const int* __restrict__ sortedEdge, const int* __restrict__ offset,
        const int* __restrict__ count, unsigned short* __restrict__ agg) {
    const int node = blockIdx.x * 4 + (threadIdx.x >> 6);
    const int lane = threadIdx.x & 63;
    if (node >= NN) return;
    const int start = offset[node];
    const int degn = count[node];
    const f32x2* __restrict__ w2 = reinterpret_cast<const f32x2*>(w);
    float ax = 0.f, ay = 0.f;
    for (int base = 0; base < degn; base += 64) {
        const int m = min(64, degn - base);
        int eid = 0;
        if (lane < m) eid = sortedEdge[start + base + lane];
        int i = 0;
        for (; i + 8 <= m; i += 8) {
            int e0 = __shfl(eid, i + 0), e1 = __shfl(eid, i + 1);
            int e2 = __shfl(eid, i + 2), e3 = __shfl(eid, i + 3);
            int e4 = __shfl(eid, i + 4), e5 = __shfl(eid, i + 5);
            int e6 = __shfl(eid, i + 6), e7 = __shfl(eid, i + 7);
            f32x2 v0 = __builtin_nontemporal_load(&w2[(size_t)e0 * 64 + lane]);
            f32x2 v1 = __builtin_nontemporal_load(&w2[(size_t)e1 * 64 + lane]);
            f32x2 v2 = __builtin_nontemporal_load(&w2[(size_t)e2 * 64 + lane]);
            f32x2 v3 = __builtin_nontemporal_load(&w2[(size_t)e3 * 64 + lane]);
            f32x2 v4 = __builtin_nontemporal_load(&w2[(size_t)e4 * 64 + lane]);
            f32x2 v5 = __builtin_nontemporal_load(&w2[(size_t)e5 * 64 + lane]);
            f32x2 v6 = __builtin_nontemporal_load(&w2[(size_t)e6 * 64 + lane]);
            f32x2 v7 = __builtin_nontemporal_load(&w2[(size_t)e7 * 64 + lane]);
            ax += ((v0.x + v1.x) + (v2.x + v3.x)) + ((v4.x + v5.x) + (v6.x + v7.x));
            ay += ((v0.y + v1.y) + (v2.y + v3.y)) + ((v4.y + v5.y) + (v6.y + v7.y));
        }
        for (; i < m; ++i) {
            int e = __shfl(eid, i);
            f32x2 v = __builtin_nontemporal_load(&w2[(size_t)e * 64 + lane]);
            ax += v.x;
            ay += v.y;
        }
    }
    unsigned int pack = (unsigned int)f2bf(ax) | ((unsigned int)f2bf(ay) << 16);
    *reinterpret_cast<unsigned int*>(agg + (size_t)node * BF + lane * 2) = pack;
}

// ------------------------------------------------- pack [W_atom|W_bond] -> bf16 (linear)
__global__ __launch_bounds__(256) void k_convert(const float* __restrict__ Wa,
        const float* __restrict__ Wb, unsigned short* __restrict__ Wc) {
    int gid = blockIdx.x * 256 + threadIdx.x;
    int j = gid / 48, cb = gid % 48;
    const float* src = (cb < 32) ? (Wa + j * AF + cb * 8) : (Wb + j * BF + (cb - 32) * 8);
    float4 a = reinterpret_cast<const float4*>(src)[0];
    float4 b = reinterpret_cast<const float4*>(src)[1];
    short8 s;
    s[0] = f2bf(a.x); s[1] = f2bf(a.y); s[2] = f2bf(a.z); s[3] = f2bf(a.w);
    s[4] = f2bf(b.x); s[5] = f2bf(b.y); s[6] = f2bf(b.z); s[7] = f2bf(b.w);
    *reinterpret_cast<short8*>(Wc + j * KT + cb * 8) = s;
}

// ------- fused node GEMM: B in regs, A LDS double-buffered, 1 barrier per chunk
#define LOADCHUNK(P, ch) do { \
    const int base_ = (ch) * 32; \
    const int g0_ = base_ + xr0, g1_ = base_ + xr1, g2_ = base_ + gr_; \
    if (g0_ < NN) { const float4* s_ = reinterpret_cast<const float4*>(x + (size_t)g0_ * AF + xkb * 8); P##xa0 = s_[0]; P##xb0 = s_[1]; } \
    else { P##xa0 = make_float4(0.f,0.f,0.f,0.f); P##xb0 = make_float4(0.f,0.f,0.f,0.f); } \
    if (g1_ < NN) { const float4* s_ = reinterpret_cast<const float4*>(x + (size_t)g1_ * AF + xkb * 8); P##xa1 = s_[0]; P##xb1 = s_[1]; } \
    else { P##xa1 = make_float4(0.f,0.f,0.f,0.f); P##xb1 = make_float4(0.f,0.f,0.f,0.f); } \
    if (g2_ < NN) { P##ga = *reinterpret_cast<const short8*>(agg + (size_t)g2_ * BF + gkb * 8); } \
    else { P##ga = short8{0,0,0,0,0,0,0,0}; } \
} while (0)

#define WRITECHUNK(P, BUF) do { \
    short8 s_; \
    s_[0]=f2bf(P##xa0.x); s_[1]=f2bf(P##xa0.y); s_[2]=f2bf(P##xa0.z); s_[3]=f2bf(P##xa0.w); \
    s_[4]=f2bf(P##xb0.x); s_[5]=f2bf(P##xb0.y); s_[6]=f2bf(P##xb0.z); s_[7]=f2bf(P##xb0.w); \
    *reinterpret_cast<short8*>((BUF) + xr0 * KT + ((xkb ^ (xr0 & 7)) << 3)) = s_; \
    s_[0]=f2bf(P##xa1.x); s_[1]=f2bf(P##xa1.y); s_[2]=f2bf(P##xa1.z); s_[3]=f2bf(P##xa1.w); \
    s_[4]=f2bf(P##xb1.x); s_[5]=f2bf(P##xb1.y); s_[6]=f2bf(P##xb1.z); s_[7]=f2bf(P##xb1.w); \
    *reinterpret_cast<short8*>((BUF) + xr1 * KT + ((xkb ^ (xr1 & 7)) << 3)) = s_; \
    *reinterpret_cast<short8*>((BUF) + gr_ * KT + (((32 + gkb) ^ (gr_ & 7)) << 3)) = P##ga; \
} while (0)

__global__ __launch_bounds__(512, 1) void k_gemm(const float* __restrict__ x,
        const unsigned short* __restrict__ agg, const int* __restrict__ deg,
        const unsigned short* __restrict__ Wc, const float* __restrict__ b_atom,
        const float* __restrict__ b_bond, float* __restrict__ out,
        float* __restrict__ colsum, float* __restrict__ colsumsq) {
    __shared__ unsigned short As0[32 * KT];
    __shared__ unsigned short As1[32 * KT];

    const int tid = threadIdx.x;
    const int cg  = blockIdx.x >> 7;
    const int rb  = blockIdx.x & 127;
    const int wid = tid >> 6, lane = tid & 63;
    const int lrow = lane & 15, lk = lane >> 4;
    const int rh = wid & 1, cq = wid >> 1;
    const int colb = cg * 128 + cq * 32;

    // B fragments in registers (one-time)
    short8 breg[2][12];
    #pragma unroll
    for (int t = 0; t < 2; ++t)
        #pragma unroll
        for (int kt = 0; kt < 12; ++kt)
            breg[t][kt] = *reinterpret_cast<const short8*>(
                Wc + (size_t)(colb + t * 16 + lrow) * KT + kt * 32 + lk * 8);

    const float ba0 = b_atom[colb + lrow],      bb0 = b_bond[colb + lrow];
    const float ba1 = b_atom[colb + 16 + lrow], bb1 = b_bond[colb + 16 + lrow];

    // ping-pong staging registers
    float4 Axa0, Axb0, Axa1, Axb1; short8 Aga;
    float4 Bxa0, Bxb0, Bxa1, Bxb1; short8 Bga;
    const int xr0 = tid >> 5, xkb = tid & 31;
    const int xr1 = 16 + xr0;
    const int gr_ = tid >> 4, gkb = tid & 15;

    float st0 = 0.f, st20 = 0.f, st1 = 0.f, st21 = 0.f;
    const int ra = rh * 16 + lrow;

    auto compute = [&](int chunk, const unsigned short* Abuf) {
        const int row0 = chunk * 32 + rh * 16 + lk * 4;
        float degv[4];
        #pragma unroll
        for (int r2 = 0; r2 < 4; ++r2)
            degv[r2] = (row0 + r2 < NN) ? (float)deg[row0 + r2] : 0.f;
        f32x4 acc0 = f32x4{0.f,0.f,0.f,0.f};
        f32x4 acc1 = f32x4{0.f,0.f,0.f,0.f};
        #pragma unroll
        for (int kt = 0; kt < 12; ++kt) {
            const int kb = kt * 4 + lk;
            short8 af = *reinterpret_cast<const short8*>(Abuf + ra * KT + ((kb ^ (ra & 7)) << 3));
            acc0 = __builtin_amdgcn_mfma_f32_16x16x32_bf16(af, breg[0][kt], acc0, 0, 0, 0);
            acc1 = __builtin_amdgcn_mfma_f32_16x16x32_bf16(af, breg[1][kt], acc1, 0, 0, 0);
        }
        #pragma unroll
        for (int r2 = 0; r2 < 4; ++r2) {
            const int gr = row0 + r2;
            float v0 = fmaxf(acc0[r2] + ba0 + degv[r2] * bb0, 0.f);
            float v1 = fmaxf(acc1[r2] + ba1 + degv[r2] * bb1, 0.f);
            if (gr < NN) {
                out[(size_t)gr * HIDN + colb + lrow]      = v0;
                out[(size_t)gr * HIDN + colb + 16 + lrow] = v1;
                st0 += v0; st20 += v0 * v0;
                st1 += v1; st21 += v1 * v1;
            }
        }
    };

    // prologue: fill As0, prefetch B
    LOADCHUNK(A, rb);
    WRITECHUNK(A, As0);
    LOADCHUNK(B, rb + 128);
    asm volatile("s_waitcnt lgkmcnt(0)" ::: "memory");
    __builtin_amdgcn_s_barrier();

    int chunk = rb;
    while (true) {
        WRITECHUNK(B, As1);              // chunk+128 data -> other buffer
        LOADCHUNK(A, chunk + 256);       // issue next-next loads
        compute(chunk, As0);
        asm volatile("s_waitcnt lgkmcnt(0)" ::: "memory");
        __builtin_amdgcn_s_barrier();
        chunk += 128;
        if (chunk >= NCHUNK) break;

        WRITECHUNK(A, As0);
        LOADCHUNK(B, chunk + 256);
        compute(chunk, As1);
        asm volatile("s_waitcnt lgkmcnt(0)" ::: "memory");
        __builtin_amdgcn_s_barrier();
        chunk += 128;
        if (chunk >= NCHUNK) break;
    }

    // flush stats
    float s, s2;
    s = st0; s2 = st20;
    s += __shfl_xor(s, 16);  s += __shfl_xor(s, 32);
    s2 += __shfl_xor(s2, 16); s2 += __shfl_xor(s2, 32);
    if (lane < 16) {
        atomicAdd(colsum + colb + lrow, s);
        atomicAdd(colsumsq + colb + lrow, s2);
    }
    s = st1; s2 = st21;
    s += __shfl_xor(s, 16);  s += __shfl_xor(s, 32);
    s2 += __shfl_xor(s2, 16); s2 += __shfl_xor(s2, 32);
    if (lane < 16) {
        atomicAdd(colsum + colb + 16 + lrow, s);
        atomicAdd(colsumsq + colb + 16 + lrow, s2);
    }
}

// ---------------------------------------------------------------- BN finalize
__global__ void k_bnfin(const float* __restrict__ colsum, const float* __restrict__ colsumsq,
        const float* __restrict__ gamma, const float* __restrict__ beta,
        float* __restrict__ scale, float* __restrict__ shift) {
    int j = threadIdx.x;
    float mean = colsum[j] * (1.f / NN);
    float var = colsumsq[j] * (1.f / NN) - mean * mean;
    float sc = gamma[j] * rsqrtf(var + 1e-5f);
    scale[j] = sc;
    shift[j] = beta[j] - mean * sc;
}

// ---------------------------------------------------------------- BN apply (in-place)
__global__ __launch_bounds__(256) void k_bnapply(float* __restrict__ out,
        const float* __restrict__ scale, const float* __restrict__ shift) {
    __shared__ float scs[HIDN], shs[HIDN];
    scs[threadIdx.x] = scale[threadIdx.x];
    shs[threadIdx.x] = shift[threadIdx.x];
    __syncthreads();
    const int total = NN * HIDN / 4;
    f32x4* __restrict__ out4 = reinterpret_cast<f32x4*>(out);
    for (int gid = blockIdx.x * 256 + threadIdx.x; gid < total; gid += gridDim.x * 256) {
        f32x4 v = out4[gid];
        const int c = (gid & 63) * 4;
        const f32x4 sc = *reinterpret_cast<const f32x4*>(&scs[c]);
        const f32x4 sh = *reinterpret_cast<const f32x4*>(&shs[c]);
        f32x4 r;
        r[0] = fmaf(v[0], sc[0], sh[0]);
        r[1] = fmaf(v[1], sc[1], sh[1]);
        r[2] = fmaf(v[2], sc[2], sh[2]);
        r[3] = fmaf(v[3], sc[3], sh[3]);
        __builtin_nontemporal_store(r, &out4[gid]);
    }
}

extern "C" void kernel_launch(void* const* d_in, const int* in_sizes, int n_in,
                              void* d_out, int out_size, void* d_ws, size_t ws_size,
                              hipStream_t stream) {
    const float* x      = (const float*)d_in[0];
    const float* w      = (const float*)d_in[1];
    const int*   dst    = (const int*)d_in[2];
    const float* W_atom = (const float*)d_in[3];
    const float* b_atom = (const float*)d_in[4];
    const float* W_bond = (const float*)d_in[5];
    const float* b_bond = (const float*)d_in[6];
    const float* gamma  = (const float*)d_in[7];
    const float* beta   = (const float*)d_in[8];
    float* out = (float*)d_out;

    // workspace layout
    unsigned short* agg = (unsigned short*)d_ws;            // NN*128 bf16
    unsigned short* Wc  = agg + (size_t)NN * BF;            // 256*384 bf16
    float* colsum   = (float*)(Wc + (size_t)HIDN * KT);     // 256
    float* colsumsq = colsum + HIDN;                        // 256
    int* count      = (int*)(colsumsq + HIDN);              // NN   (zeroed)
    int* offset     = count + NN;                           // NN
    int* cursor     = offset + NN;                          // NN
    int* sortedEdge = cursor + NN;                          // NE
    float* scale    = (float*)(sortedEdge + NE);            // 256
    float* shift    = scale + HIDN;                         // 256
    int* blockSum   = (int*)(shift + HIDN);                 // 64
    int* blockBase  = blockSum + 64;                        // 64

    // zero colsum+colsumsq+count (contiguous)
    hipMemsetAsync((void*)colsum, 0, (size_t)(2 * HIDN + NN) * 4, stream);

    k_convert<<<48, 256, 0, stream>>>(W_atom, W_bond, Wc);
    k_hist<<<(NE / 4 + 255) / 256, 256, 0, stream>>>((const int4*)dst, count);
    k_scanA<<<49, 1024, 0, stream>>>(count, offset, blockSum);
    k_scanB<<<1, 64, 0, stream>>>(blockSum, blockBase);
    k_scanC<<<49, 1024, 0, stream>>>(offset, cursor, blockBase);
    k_sortscatter<<<(NE / 4 + 255) / 256, 256, 0, stream>>>((const int4*)dst, cursor, sortedEdge);
    k_gather<<<(NN + 3) / 4, 256, 0, stream>>>(w, sortedEdge, offset, count, agg);
    k_gemm<<<256, 512, 0, stream>>>(x, agg, count, Wc, b_atom, b_bond,
                                    out, colsum, colsumsq);
    k_bnfin<<<1, 256, 0, stream>>>(colsum, colsumsq, gamma, beta, scale, shift);
    k_bnapply<<<2048, 256, 0, stream>>>(out, scale, shift);
}